// Round 2
// baseline (378.696 us; speedup 1.0000x reference)
//
#include <hip/hip_runtime.h>

#define NN 8192
#define WW_ 128
#define RR 4
#define EPSF 1e-8f

// scratch float offsets (ws needed: ~1.12 MB)
#define S_LOGITS 0
#define S_ALLOC  8192
#define S_WW     16384
#define S_RET    24576
#define S_RC     32768      // 8192*4
#define S_FWD    65536      // 8192*4
#define S_BWD    98304      // 8192*4
#define S_APART  131072     // 8*8192 masked-product partials
#define S_CPART  196608     // 8*8192 rank-count partials
#define S_G      262144     // 8192 canonical alloc values
#define S_RANK   270336     // 8192 ints
#define S_SCAL   278528     // 32 scalars: [0]=|wk| [1..4]=|rk_r| [5]=sm_max [6]=sm_sum [7]=ww_sum

// output float offsets
#define O_RV 0
#define O_NM 512
#define O_NU 1049088
#define O_NP 1057280
#define O_NL 1065472
#define O_NR 68174336

// ---- norms of write_key and read_keys ----
__global__ void k_prep(const float* __restrict__ wk, const float* __restrict__ rk,
                       float* __restrict__ scal) {
    __shared__ float sb[5][128];
    int t = threadIdx.x;
    float w = wk[t];
    sb[0][t] = w * w;
    float4 k = *(const float4*)&rk[t * 4];
    sb[1][t] = k.x * k.x; sb[2][t] = k.y * k.y; sb[3][t] = k.z * k.z; sb[4][t] = k.w * k.w;
    __syncthreads();
    for (int s = 64; s > 0; s >>= 1) {
        if (t < s) {
            #pragma unroll
            for (int q = 0; q < 5; q++) sb[q][t] += sb[q][t + s];
        }
        __syncthreads();
    }
    if (t < 5) scal[t] = sqrtf(sb[t][0]);
}

// ---- per-row: content logits, retention, read_vectors partials ----
__global__ __launch_bounds__(256) void k_rowstats(
    const float* __restrict__ mem, const float* __restrict__ rw,
    const float* __restrict__ wk, const float* __restrict__ fg,
    const float* __restrict__ wstr, const float* __restrict__ scal,
    float* __restrict__ rv_out, float* __restrict__ logits, float* __restrict__ ret)
{
    int lane = threadIdx.x & 63;
    int wave = (blockIdx.x << 2) + (threadIdx.x >> 6);   // 0..511 (grid=128)
    int c = lane * 2;
    float2 wk2 = *(const float2*)&wk[c];
    float4 fg4 = *(const float4*)&fg[0];
    float ws = wstr[0];
    float wkn = scal[0];
    float arv[2][4];
    #pragma unroll
    for (int a = 0; a < 2; a++)
        #pragma unroll
        for (int r = 0; r < 4; r++) arv[a][r] = 0.f;
    int i0 = wave * 16;
    for (int t = 0; t < 16; t++) {
        int i = i0 + t;
        float2 m2 = *(const float2*)&mem[i * WW_ + c];
        float4 rwi = *(const float4*)&rw[i * 4];
        float dp = m2.x * wk2.x + m2.y * wk2.y;
        float nq = m2.x * m2.x + m2.y * m2.y;
        #pragma unroll
        for (int s = 1; s < 64; s <<= 1) { dp += __shfl_xor(dp, s); nq += __shfl_xor(nq, s); }
        arv[0][0] += m2.x * rwi.x; arv[0][1] += m2.x * rwi.y; arv[0][2] += m2.x * rwi.z; arv[0][3] += m2.x * rwi.w;
        arv[1][0] += m2.y * rwi.x; arv[1][1] += m2.y * rwi.y; arv[1][2] += m2.y * rwi.z; arv[1][3] += m2.y * rwi.w;
        if (lane == 0) {
            float denom = fmaxf(sqrtf(nq) * wkn, EPSF);
            logits[i] = dp / denom * ws;
            ret[i] = (1.f - rwi.x * fg4.x) * (1.f - rwi.y * fg4.y) *
                     (1.f - rwi.z * fg4.z) * (1.f - rwi.w * fg4.w);
        }
    }
    #pragma unroll
    for (int a = 0; a < 2; a++)
        #pragma unroll
        for (int r = 0; r < 4; r++)
            atomicAdd(&rv_out[(c + a) * 4 + r], arv[a][r]);
}

// ---- allocation weighting: partial masked products + rank counts over j-chunks ----
__global__ __launch_bounds__(256) void k_apart(const float* __restrict__ u,
                                               float* __restrict__ apart,
                                               float* __restrict__ cpart) {
    __shared__ float su[1024];
    int jc = blockIdx.x & 7;
    int ib = blockIdx.x >> 3;
    int t = threadIdx.x;
    for (int q = t; q < 1024; q += 256) su[q] = u[jc * 1024 + q];
    __syncthreads();
    int i = ib * 256 + t;
    float ui = u[i];
    float p0 = 1.f, p1 = 1.f, p2 = 1.f, p3 = 1.f;
    int c0 = 0, c1 = 0, c2 = 0, c3 = 0;
    int jbase = jc * 1024;
    for (int q = 0; q < 1024; q += 4) {
        float a0 = su[q], a1 = su[q + 1], a2 = su[q + 2], a3 = su[q + 3];
        int j0 = jbase + q;
        bool m0 = (a0 < ui) || (a0 == ui && j0     < i);
        bool m1 = (a1 < ui) || (a1 == ui && j0 + 1 < i);
        bool m2 = (a2 < ui) || (a2 == ui && j0 + 2 < i);
        bool m3 = (a3 < ui) || (a3 == ui && j0 + 3 < i);
        p0 *= m0 ? a0 : 1.f; c0 += m0;
        p1 *= m1 ? a1 : 1.f; c1 += m1;
        p2 *= m2 ? a2 : 1.f; c2 += m2;
        p3 *= m3 ? a3 : 1.f; c3 += m3;
    }
    apart[jc * NN + i] = (p0 * p1) * (p2 * p3);
    cpart[jc * NN + i] = (float)((c0 + c1) + (c2 + c3));
}

// ---- combine partials: canonical alloc g[i] and stable rank[i] ----
__global__ void k_grank(const float* __restrict__ u, const float* __restrict__ apart,
                        const float* __restrict__ cpart,
                        float* __restrict__ g, int* __restrict__ rank) {
    int i = blockIdx.x * 256 + threadIdx.x;
    float p = 1.f, c = 0.f;
    #pragma unroll
    for (int jc = 0; jc < 8; jc++) { p *= apart[jc * NN + i]; c += cpart[jc * NN + i]; }
    g[i] = (1.f - u[i]) * p;
    rank[i] = (int)c;
}

// ---- reference does alloc_sorted[order] (gather, not inverse-perm):
//      out[rank[rank[m]]] = g[m]  reproduces it exactly ----
__global__ void k_scatter(const float* __restrict__ g, const int* __restrict__ rank,
                          float* __restrict__ alloc) {
    int m = blockIdx.x * 256 + threadIdx.x;
    alloc[rank[rank[m]]] = g[m];
}

// ---- softmax stats over content logits ----
__global__ __launch_bounds__(256) void k_softmax(const float* __restrict__ logits,
                                                 float* __restrict__ scal) {
    __shared__ float sb[256];
    int t = threadIdx.x;
    float mx = -1e30f;
    for (int q = t; q < NN; q += 256) mx = fmaxf(mx, logits[q]);
    sb[t] = mx; __syncthreads();
    for (int s = 128; s > 0; s >>= 1) { if (t < s) sb[t] = fmaxf(sb[t], sb[t + s]); __syncthreads(); }
    mx = sb[0]; __syncthreads();
    float sm = 0.f;
    for (int q = t; q < NN; q += 256) sm += __expf(logits[q] - mx);
    sb[t] = sm; __syncthreads();
    for (int s = 128; s > 0; s >>= 1) { if (t < s) sb[t] += sb[t + s]; __syncthreads(); }
    if (t == 0) { scal[5] = mx; scal[6] = sb[0]; }
}

// ---- write weighting + its sum ----
__global__ __launch_bounds__(256) void k_ww(
    const float* __restrict__ logits, const float* __restrict__ alloc,
    const float* __restrict__ ag, const float* __restrict__ wg_,
    float* __restrict__ scal, float* __restrict__ ww)
{
    __shared__ float sb[256];
    int t = threadIdx.x;
    int i = blockIdx.x * 256 + t;
    float mx = scal[5], inv = 1.f / scal[6];
    float ga = ag[0], wg = wg_[0];
    float cw = __expf(logits[i] - mx) * inv;
    float v = wg * (ga * alloc[i] + (1.f - ga) * cw);
    ww[i] = v;
    sb[t] = v; __syncthreads();
    for (int s = 128; s > 0; s >>= 1) { if (t < s) sb[t] += sb[t + s]; __syncthreads(); }
    if (t == 0) atomicAdd(&scal[7], sb[0]);
}

// ---- per-row epilogue: new_memory, usage, precedence, read_content ----
__global__ __launch_bounds__(256) void k_rownew(
    const float* __restrict__ mem, const float* __restrict__ ww,
    const float* __restrict__ u, const float* __restrict__ ret,
    const float* __restrict__ prec, const float* __restrict__ er,
    const float* __restrict__ wv, const float* __restrict__ rk,
    const float* __restrict__ rstr, const float* __restrict__ scal,
    float* __restrict__ nm_out, float* __restrict__ nu_out,
    float* __restrict__ np_out, float* __restrict__ rc_out)
{
    int lane = threadIdx.x & 63;
    int wave = (blockIdx.x << 2) + (threadIdx.x >> 6);   // 0..1023 (grid=256)
    int c = lane * 2;
    float2 er2 = *(const float2*)&er[c];
    float2 wv2 = *(const float2*)&wv[c];
    float4 rka = *(const float4*)&rk[c * 4];
    float4 rkb = *(const float4*)&rk[(c + 1) * 4];
    float rkn0 = scal[1], rkn1 = scal[2], rkn2 = scal[3], rkn3 = scal[4];
    float wsum = scal[7];
    float4 rs4 = *(const float4*)&rstr[0];
    int i0 = wave * 8;
    for (int t = 0; t < 8; t++) {
        int i = i0 + t;
        float wwi = ww[i];
        float2 m2 = *(const float2*)&mem[i * WW_ + c];
        float nx = m2.x * (1.f - wwi * er2.x) + wwi * wv2.x;
        float ny = m2.y * (1.f - wwi * er2.y) + wwi * wv2.y;
        float2 nm2; nm2.x = nx; nm2.y = ny;
        *(float2*)&nm_out[i * WW_ + c] = nm2;
        float nq = nx * nx + ny * ny;
        float d0 = nx * rka.x + ny * rkb.x;
        float d1 = nx * rka.y + ny * rkb.y;
        float d2 = nx * rka.z + ny * rkb.z;
        float d3 = nx * rka.w + ny * rkb.w;
        #pragma unroll
        for (int s = 1; s < 64; s <<= 1) {
            nq += __shfl_xor(nq, s);
            d0 += __shfl_xor(d0, s); d1 += __shfl_xor(d1, s);
            d2 += __shfl_xor(d2, s); d3 += __shfl_xor(d3, s);
        }
        if (lane == 0) {
            float nrm = sqrtf(nq);
            float l0 = d0 / (nrm * rkn0) * rs4.x;
            float l1 = d1 / (nrm * rkn1) * rs4.y;
            float l2 = d2 / (nrm * rkn2) * rs4.z;
            float l3 = d3 / (nrm * rkn3) * rs4.w;
            float m4 = fmaxf(fmaxf(l0, l1), fmaxf(l2, l3));
            float e0 = __expf(l0 - m4), e1 = __expf(l1 - m4);
            float e2 = __expf(l2 - m4), e3 = __expf(l3 - m4);
            float si = 1.f / (e0 + e1 + e2 + e3);
            float4 rc; rc.x = e0 * si; rc.y = e1 * si; rc.z = e2 * si; rc.w = e3 * si;
            *(float4*)&rc_out[i * 4] = rc;
            float ui = u[i];
            nu_out[i] = (ui + wwi - ui * wwi) * ret[i];
            np_out[i] = (1.f - wsum) * prec[i] + wwi;
        }
    }
}

// ---- THE big pass: new_link + fused fwd/bwd weighted row/col sums ----
__global__ __launch_bounds__(256) void k_link(
    const float* __restrict__ link, const float* __restrict__ ww,
    const float* __restrict__ prec, const float* __restrict__ rw,
    float* __restrict__ nl_out, float* __restrict__ fwd, float* __restrict__ bwd)
{
    __shared__ float fl[4][1024];
    int lane = threadIdx.x & 63;
    int w = threadIdx.x >> 6;
    int j = blockIdx.x * 256 + lane * 4;
    int i0 = blockIdx.y * 256 + w * 64;
    float4 wwj = *(const float4*)&ww[j];
    float4 pj  = *(const float4*)&prec[j];
    float4 rwj0 = *(const float4*)&rw[(j    ) * 4];
    float4 rwj1 = *(const float4*)&rw[(j + 1) * 4];
    float4 rwj2 = *(const float4*)&rw[(j + 2) * 4];
    float4 rwj3 = *(const float4*)&rw[(j + 3) * 4];
    float fa[4][4];
    #pragma unroll
    for (int a = 0; a < 4; a++)
        #pragma unroll
        for (int r = 0; r < 4; r++) fa[a][r] = 0.f;

    for (int t = 0; t < 64; t++) {
        int i = i0 + t;
        float wwi = ww[i];
        float4 rwi = *(const float4*)&rw[i * 4];
        float c0 = 1.f - wwi;
        size_t off = (size_t)i * NN + j;
        float4 Lv = *(const float4*)&link[off];
        float4 e;
        e.x = (c0 - wwj.x) * Lv.x + wwi * pj.x;
        e.y = (c0 - wwj.y) * Lv.y + wwi * pj.y;
        e.z = (c0 - wwj.z) * Lv.z + wwi * pj.z;
        e.w = (c0 - wwj.w) * Lv.w + wwi * pj.w;
        *(float4*)&nl_out[off] = e;
        // fwd (column sums weighted by rw[i])
        fa[0][0] += e.x * rwi.x; fa[0][1] += e.x * rwi.y; fa[0][2] += e.x * rwi.z; fa[0][3] += e.x * rwi.w;
        fa[1][0] += e.y * rwi.x; fa[1][1] += e.y * rwi.y; fa[1][2] += e.y * rwi.z; fa[1][3] += e.y * rwi.w;
        fa[2][0] += e.z * rwi.x; fa[2][1] += e.z * rwi.y; fa[2][2] += e.z * rwi.z; fa[2][3] += e.z * rwi.w;
        fa[3][0] += e.w * rwi.x; fa[3][1] += e.w * rwi.y; fa[3][2] += e.w * rwi.z; fa[3][3] += e.w * rwi.w;
        // bwd (row sum weighted by rw[j]) — pair-merged butterfly: 8 shuffles
        float b0 = e.x * rwj0.x + e.y * rwj1.x + e.z * rwj2.x + e.w * rwj3.x;
        float b1 = e.x * rwj0.y + e.y * rwj1.y + e.z * rwj2.y + e.w * rwj3.y;
        float b2 = e.x * rwj0.z + e.y * rwj1.z + e.z * rwj2.z + e.w * rwj3.z;
        float b3 = e.x * rwj0.w + e.y * rwj1.w + e.z * rwj2.w + e.w * rwj3.w;
        float u01 = (lane & 1) ? b0 : b1;
        float v01 = __shfl_xor(u01, 1);
        float A = ((lane & 1) ? b1 : b0) + v01;
        float u23 = (lane & 1) ? b2 : b3;
        float v23 = __shfl_xor(u23, 1);
        float B = ((lane & 1) ? b3 : b2) + v23;
        float uu = (lane & 2) ? A : B;
        float vv = __shfl_xor(uu, 2);
        float S = ((lane & 2) ? B : A) + vv;
        #pragma unroll
        for (int s = 4; s < 64; s <<= 1) S += __shfl_xor(S, s);
        if (lane < 4) atomicAdd(&bwd[i * 4 + lane], S);
    }
    // cross-wave combine of fwd partials, then one atomic per (col,r)
    #pragma unroll
    for (int a = 0; a < 4; a++)
        #pragma unroll
        for (int r = 0; r < 4; r++)
            fl[w][(lane * 4 + a) * 4 + r] = fa[a][r];
    __syncthreads();
    int col = threadIdx.x;
    #pragma unroll
    for (int r = 0; r < 4; r++) {
        float s = fl[0][col * 4 + r] + fl[1][col * 4 + r] + fl[2][col * 4 + r] + fl[3][col * 4 + r];
        atomicAdd(&fwd[(blockIdx.x * 256 + col) * 4 + r], s);
    }
}

// ---- combine into new read weightings ----
__global__ void k_final(const float* __restrict__ fwd, const float* __restrict__ bwd,
                        const float* __restrict__ rc, const float* __restrict__ modes,
                        float* __restrict__ out) {
    int idx = blockIdx.x * 256 + threadIdx.x;   // < 32768
    int r = idx & 3;
    float m0 = modes[r * 3], m1 = modes[r * 3 + 1], m2 = modes[r * 3 + 2];
    out[idx] = bwd[idx] * m0 + rc[idx] * m1 + fwd[idx] * m2;
}

extern "C" void kernel_launch(void* const* d_in, const int* in_sizes, int n_in,
                              void* d_out, int out_size, void* d_ws, size_t ws_size,
                              hipStream_t stream) {
    const float* mem   = (const float*)d_in[0];
    const float* u     = (const float*)d_in[1];
    const float* prec  = (const float*)d_in[2];
    const float* link  = (const float*)d_in[3];
    const float* rw    = (const float*)d_in[4];
    const float* rk    = (const float*)d_in[5];
    const float* rstr  = (const float*)d_in[6];
    const float* wk    = (const float*)d_in[7];
    const float* wstr  = (const float*)d_in[8];
    const float* er    = (const float*)d_in[9];
    const float* wv    = (const float*)d_in[10];
    const float* fg    = (const float*)d_in[11];
    const float* ag    = (const float*)d_in[12];
    const float* wg    = (const float*)d_in[13];
    const float* modes = (const float*)d_in[14];
    float* out = (float*)d_out;
    float* ws  = (float*)d_ws;

    hipMemsetAsync(out + O_RV, 0, 512 * sizeof(float), stream);
    hipMemsetAsync(ws + S_FWD, 0, 65536 * sizeof(float), stream);   // fwd + bwd
    hipMemsetAsync(ws + S_SCAL, 0, 32 * sizeof(float), stream);

    k_prep<<<1, 128, 0, stream>>>(wk, rk, ws + S_SCAL);
    k_rowstats<<<128, 256, 0, stream>>>(mem, rw, wk, fg, wstr, ws + S_SCAL,
                                        out + O_RV, ws + S_LOGITS, ws + S_RET);
    k_apart<<<256, 256, 0, stream>>>(u, ws + S_APART, ws + S_CPART);
    k_grank<<<32, 256, 0, stream>>>(u, ws + S_APART, ws + S_CPART,
                                    ws + S_G, (int*)(ws + S_RANK));
    k_scatter<<<32, 256, 0, stream>>>(ws + S_G, (const int*)(ws + S_RANK), ws + S_ALLOC);
    k_softmax<<<1, 256, 0, stream>>>(ws + S_LOGITS, ws + S_SCAL);
    k_ww<<<32, 256, 0, stream>>>(ws + S_LOGITS, ws + S_ALLOC, ag, wg, ws + S_SCAL, ws + S_WW);
    k_rownew<<<256, 256, 0, stream>>>(mem, ws + S_WW, u, ws + S_RET, prec, er, wv, rk, rstr,
                                      ws + S_SCAL, out + O_NM, out + O_NU, out + O_NP, ws + S_RC);
    dim3 lg(32, 32);
    k_link<<<lg, 256, 0, stream>>>(link, ws + S_WW, prec, rw, out + O_NL, ws + S_FWD, ws + S_BWD);
    k_final<<<128, 256, 0, stream>>>(ws + S_FWD, ws + S_BWD, ws + S_RC, modes, out + O_NR);
}

// Round 4
// 196.348 us; speedup vs baseline: 1.9287x; 1.9287x over previous
//
#include <hip/hip_runtime.h>

#define NN 8192
#define WW_ 128
#define EPSF 1e-8f

typedef float vfloat4 __attribute__((ext_vector_type(4)));

// ws float offsets (total ~590 KB, well under proven 1.11 MB)
#define S_LOGITS 0
#define S_ALLOC  8192
#define S_WW     16384
#define S_RET    24576
#define S_G      32768
#define S_RANK   40960
#define S_RC     49152      // 8192*4
#define S_FWD    81920      // 8192*4
#define S_BWD    114688     // 8192*4 (contiguous after FWD)
#define S_SCAL   147456     // 32 scalars: [6]=sum exp(logit), [8]=sum alloc

// output float offsets
#define O_RV 0
#define O_NM 512
#define O_NU 1049088
#define O_NP 1057280
#define O_NL 1065472
#define O_NR 68174336

// scratch carved out of the (not-yet-written) new_link output region
#define P_APART 0           // 16*8192
#define P_CPART 131072      // 16*8192
#define P_RVP   262144      // 256*512 rv partials

// ---- per-row: content logits, retention, read_vectors partials (no atomics) ----
__global__ __launch_bounds__(256, 4) void k_rowstats(
    const float* __restrict__ mem, const float* __restrict__ rw,
    const float* __restrict__ wk, const float* __restrict__ fg,
    const float* __restrict__ wstr,
    float* __restrict__ rvp, float* __restrict__ logits, float* __restrict__ ret,
    float* __restrict__ scal)
{
    __shared__ float sb[4][512];
    int lane = threadIdx.x & 63;
    int w = threadIdx.x >> 6;
    int wave = (blockIdx.x << 2) + w;            // 0..1023
    int c = lane * 2;
    float2 wk2 = *(const float2*)&wk[c];
    float4 fg4 = *(const float4*)&fg[0];
    float ws = wstr[0];
    // |write_key| via butterfly (all lanes get full sum)
    float nw = wk2.x * wk2.x + wk2.y * wk2.y;
    #pragma unroll
    for (int s = 1; s < 64; s <<= 1) nw += __shfl_xor(nw, s);
    float wkn = sqrtf(nw);

    float arv[2][4];
    #pragma unroll
    for (int a = 0; a < 2; a++)
        #pragma unroll
        for (int r = 0; r < 4; r++) arv[a][r] = 0.f;
    float se = 0.f;
    int i0 = wave * 8;
    for (int t = 0; t < 8; t++) {
        int i = i0 + t;
        float2 m2 = *(const float2*)&mem[i * WW_ + c];
        float4 rwi = *(const float4*)&rw[i * 4];
        float dp = m2.x * wk2.x + m2.y * wk2.y;
        float nq = m2.x * m2.x + m2.y * m2.y;
        #pragma unroll
        for (int s = 1; s < 64; s <<= 1) { dp += __shfl_xor(dp, s); nq += __shfl_xor(nq, s); }
        arv[0][0] += m2.x * rwi.x; arv[0][1] += m2.x * rwi.y; arv[0][2] += m2.x * rwi.z; arv[0][3] += m2.x * rwi.w;
        arv[1][0] += m2.y * rwi.x; arv[1][1] += m2.y * rwi.y; arv[1][2] += m2.y * rwi.z; arv[1][3] += m2.y * rwi.w;
        if (lane == 0) {
            float denom = fmaxf(sqrtf(nq) * wkn, EPSF);
            float lg = dp / denom * ws;          // |lg| <= ws <= 2: exp is fp32-safe, no max needed
            logits[i] = lg;
            ret[i] = (1.f - rwi.x * fg4.x) * (1.f - rwi.y * fg4.y) *
                     (1.f - rwi.z * fg4.z) * (1.f - rwi.w * fg4.w);
            se += __expf(lg);
        }
    }
    if (lane == 0) atomicAdd(&scal[6], se);
    // block-level rv partial
    #pragma unroll
    for (int a = 0; a < 2; a++)
        #pragma unroll
        for (int r = 0; r < 4; r++)
            sb[w][(c + a) * 4 + r] = arv[a][r];
    __syncthreads();
    for (int idx = threadIdx.x; idx < 512; idx += 256)
        rvp[blockIdx.x * 512 + idx] = sb[0][idx] + sb[1][idx] + sb[2][idx] + sb[3][idx];
}

// ---- allocation partials (masked products + rank counts); also zeroes fwd/bwd ----
__global__ __launch_bounds__(256) void k_apart(const float* __restrict__ u,
                                               float* __restrict__ apart,
                                               float* __restrict__ cpart,
                                               float* __restrict__ fbzero) {
    __shared__ float su[512];
    int gtid = blockIdx.x * 256 + threadIdx.x;       // grid 512 -> 131072 threads
    if (gtid < 65536) fbzero[gtid] = 0.f;            // zero fwd+bwd
    int jc = blockIdx.x >> 5;                        // 0..15
    int ib = blockIdx.x & 31;
    int t = threadIdx.x;
    for (int q = t; q < 512; q += 256) su[q] = u[jc * 512 + q];
    __syncthreads();
    int i = ib * 256 + t;
    float ui = u[i];
    float p0 = 1.f, p1 = 1.f, p2 = 1.f, p3 = 1.f;
    int c0 = 0, c1 = 0, c2 = 0, c3 = 0;
    int jbase = jc * 512;
    for (int q = 0; q < 512; q += 4) {
        float a0 = su[q], a1 = su[q + 1], a2 = su[q + 2], a3 = su[q + 3];
        int j0 = jbase + q;
        bool m0 = (a0 < ui) || (a0 == ui && j0     < i);
        bool m1 = (a1 < ui) || (a1 == ui && j0 + 1 < i);
        bool m2 = (a2 < ui) || (a2 == ui && j0 + 2 < i);
        bool m3 = (a3 < ui) || (a3 == ui && j0 + 3 < i);
        p0 *= m0 ? a0 : 1.f; c0 += m0;
        p1 *= m1 ? a1 : 1.f; c1 += m1;
        p2 *= m2 ? a2 : 1.f; c2 += m2;
        p3 *= m3 ? a3 : 1.f; c3 += m3;
    }
    apart[jc * NN + i] = (p0 * p1) * (p2 * p3);
    cpart[jc * NN + i] = (float)((c0 + c1) + (c2 + c3));
}

// ---- combine partials -> g[i], rank[i], sum(g); blocks 0,1 also reduce rv ----
__global__ __launch_bounds__(256) void k_grank(
    const float* __restrict__ u, const float* __restrict__ apart,
    const float* __restrict__ cpart, const float* __restrict__ rvp,
    float* __restrict__ g, int* __restrict__ rank,
    float* __restrict__ scal, float* __restrict__ rv_out) {
    __shared__ float sb[256];
    int i = blockIdx.x * 256 + threadIdx.x;
    float p = 1.f, c = 0.f;
    #pragma unroll
    for (int jc = 0; jc < 16; jc++) { p *= apart[jc * NN + i]; c += cpart[jc * NN + i]; }
    float gi = (1.f - u[i]) * p;
    g[i] = gi;
    rank[i] = (int)c;
    sb[threadIdx.x] = gi; __syncthreads();
    for (int s = 128; s > 0; s >>= 1) { if (threadIdx.x < s) sb[threadIdx.x] += sb[threadIdx.x + s]; __syncthreads(); }
    if (threadIdx.x == 0) atomicAdd(&scal[8], sb[0]);
    if (blockIdx.x < 2) {
        int idx = blockIdx.x * 256 + threadIdx.x;    // 0..511
        float acc = 0.f;
        for (int pb = 0; pb < 256; pb++) acc += rvp[pb * 512 + idx];
        rv_out[idx] = acc;
    }
}

// ---- reference's alloc_sorted[order] gather == out[rank[rank[m]]] = g[m] ----
__global__ void k_scatter(const float* __restrict__ g, const int* __restrict__ rank,
                          float* __restrict__ alloc) {
    int m = blockIdx.x * 256 + threadIdx.x;
    alloc[rank[rank[m]]] = g[m];
}

// ---- per-row epilogue: ww (inline), new_memory, usage, precedence, read_content ----
__global__ __launch_bounds__(256, 4) void k_rownew(
    const float* __restrict__ mem, const float* __restrict__ logits,
    const float* __restrict__ alloc, const float* __restrict__ u,
    const float* __restrict__ ret, const float* __restrict__ prec,
    const float* __restrict__ er, const float* __restrict__ wv,
    const float* __restrict__ rk, const float* __restrict__ rstr,
    const float* __restrict__ ag, const float* __restrict__ wg_,
    const float* __restrict__ scal,
    float* __restrict__ ww_out, float* __restrict__ nm_out,
    float* __restrict__ nu_out, float* __restrict__ np_out, float* __restrict__ rc_out)
{
    int lane = threadIdx.x & 63;
    int wave = (blockIdx.x << 2) + (threadIdx.x >> 6);   // 0..2047 (grid 512)
    int c = lane * 2;
    float2 er2 = *(const float2*)&er[c];
    float2 wv2 = *(const float2*)&wv[c];
    float4 rka = *(const float4*)&rk[c * 4];
    float4 rkb = *(const float4*)&rk[(c + 1) * 4];
    float4 rs4 = *(const float4*)&rstr[0];
    // read-key norms via butterflies
    float n0 = rka.x * rka.x + rkb.x * rkb.x;
    float n1 = rka.y * rka.y + rkb.y * rkb.y;
    float n2 = rka.z * rka.z + rkb.z * rkb.z;
    float n3 = rka.w * rka.w + rkb.w * rkb.w;
    #pragma unroll
    for (int s = 1; s < 64; s <<= 1) {
        n0 += __shfl_xor(n0, s); n1 += __shfl_xor(n1, s);
        n2 += __shfl_xor(n2, s); n3 += __shfl_xor(n3, s);
    }
    float rkn0 = sqrtf(n0), rkn1 = sqrtf(n1), rkn2 = sqrtf(n2), rkn3 = sqrtf(n3);
    float invS = 1.f / scal[6];
    float Sg = scal[8];
    float ga = ag[0], wg = wg_[0];
    float wsum = wg * (ga * Sg + (1.f - ga));            // sum(content)==1 exactly
    int i0 = wave * 4;
    for (int t = 0; t < 4; t++) {
        int i = i0 + t;
        float wwi = wg * (ga * alloc[i] + (1.f - ga) * __expf(logits[i]) * invS);
        float2 m2 = *(const float2*)&mem[i * WW_ + c];
        float nx = m2.x * (1.f - wwi * er2.x) + wwi * wv2.x;
        float ny = m2.y * (1.f - wwi * er2.y) + wwi * wv2.y;
        float2 nm2; nm2.x = nx; nm2.y = ny;
        *(float2*)&nm_out[i * WW_ + c] = nm2;
        float nq = nx * nx + ny * ny;
        float d0 = nx * rka.x + ny * rkb.x;
        float d1 = nx * rka.y + ny * rkb.y;
        float d2 = nx * rka.z + ny * rkb.z;
        float d3 = nx * rka.w + ny * rkb.w;
        #pragma unroll
        for (int s = 1; s < 64; s <<= 1) {
            nq += __shfl_xor(nq, s);
            d0 += __shfl_xor(d0, s); d1 += __shfl_xor(d1, s);
            d2 += __shfl_xor(d2, s); d3 += __shfl_xor(d3, s);
        }
        if (lane == 0) {
            float nrm = sqrtf(nq);
            float l0 = d0 / (nrm * rkn0) * rs4.x;
            float l1 = d1 / (nrm * rkn1) * rs4.y;
            float l2 = d2 / (nrm * rkn2) * rs4.z;
            float l3 = d3 / (nrm * rkn3) * rs4.w;
            float m4 = fmaxf(fmaxf(l0, l1), fmaxf(l2, l3));
            float e0 = __expf(l0 - m4), e1 = __expf(l1 - m4);
            float e2 = __expf(l2 - m4), e3 = __expf(l3 - m4);
            float si = 1.f / (e0 + e1 + e2 + e3);
            float4 rc; rc.x = e0 * si; rc.y = e1 * si; rc.z = e2 * si; rc.w = e3 * si;
            *(float4*)&rc_out[i * 4] = rc;
            ww_out[i] = wwi;
            float ui = u[i];
            nu_out[i] = (ui + wwi - ui * wwi) * ret[i];
            np_out[i] = (1.f - wsum) * prec[i] + wwi;
        }
    }
}

// ---- THE big pass: new_link (nt-stores) + fused fwd/bwd reductions ----
__global__ __launch_bounds__(256, 4) void k_link(
    const float* __restrict__ link, const float* __restrict__ ww,
    const float* __restrict__ prec, const float* __restrict__ rw,
    float* __restrict__ nl_out, float* __restrict__ fwd, float* __restrict__ bwd)
{
    __shared__ float part[64][16][4];     // 16 KB bwd partials
    __shared__ float fl[4][256][4];       // 16 KB fwd combine
    const int lane = threadIdx.x & 63;
    const int w = threadIdx.x >> 6;
    const int j = blockIdx.x * 256 + lane * 4;

    const float4 wwj = *(const float4*)&ww[j];
    const float4 pj  = *(const float4*)&prec[j];
    const float4 rwj0 = *(const float4*)&rw[j * 4];
    const float4 rwj1 = *(const float4*)&rw[j * 4 + 4];
    const float4 rwj2 = *(const float4*)&rw[j * 4 + 8];
    const float4 rwj3 = *(const float4*)&rw[j * 4 + 12];

    float fa[4][4];
    #pragma unroll
    for (int a = 0; a < 4; a++)
        #pragma unroll
        for (int r = 0; r < 4; r++) fa[a][r] = 0.f;

    for (int sub = 0; sub < 4; ++sub) {
        const int i00 = blockIdx.y * 256 + sub * 64;
        const int irow0 = i00 + w * 16;
        #pragma unroll 4
        for (int t = 0; t < 16; ++t) {
            const int i = irow0 + t;
            const float wwi = ww[i];
            const float4 rwi = *(const float4*)&rw[i * 4];
            const size_t off = (size_t)i * NN + j;
            const float4 Lv = *(const float4*)&link[off];
            const float c0 = 1.f - wwi;
            float4 e;
            e.x = (c0 - wwj.x) * Lv.x + wwi * pj.x;
            e.y = (c0 - wwj.y) * Lv.y + wwi * pj.y;
            e.z = (c0 - wwj.z) * Lv.z + wwi * pj.z;
            e.w = (c0 - wwj.w) * Lv.w + wwi * pj.w;
            vfloat4 ev; ev.x = e.x; ev.y = e.y; ev.z = e.z; ev.w = e.w;
            __builtin_nontemporal_store(ev, (vfloat4*)&nl_out[off]);
            // fwd: column sums weighted by rw[i]
            fa[0][0] += e.x * rwi.x; fa[0][1] += e.x * rwi.y; fa[0][2] += e.x * rwi.z; fa[0][3] += e.x * rwi.w;
            fa[1][0] += e.y * rwi.x; fa[1][1] += e.y * rwi.y; fa[1][2] += e.y * rwi.z; fa[1][3] += e.y * rwi.w;
            fa[2][0] += e.z * rwi.x; fa[2][1] += e.z * rwi.y; fa[2][2] += e.z * rwi.z; fa[2][3] += e.z * rwi.w;
            fa[3][0] += e.w * rwi.x; fa[3][1] += e.w * rwi.y; fa[3][2] += e.w * rwi.z; fa[3][3] += e.w * rwi.w;
            // bwd: per-lane partial over its 4 cols, 3-shuffle pair-merge
            float b0 = e.x * rwj0.x + e.y * rwj1.x + e.z * rwj2.x + e.w * rwj3.x;
            float b1 = e.x * rwj0.y + e.y * rwj1.y + e.z * rwj2.y + e.w * rwj3.y;
            float b2 = e.x * rwj0.z + e.y * rwj1.z + e.z * rwj2.z + e.w * rwj3.z;
            float b3 = e.x * rwj0.w + e.y * rwj1.w + e.z * rwj2.w + e.w * rwj3.w;
            float u01 = (lane & 1) ? b0 : b1;
            float v01 = __shfl_xor(u01, 1);
            float A = ((lane & 1) ? b1 : b0) + v01;
            float u23 = (lane & 1) ? b2 : b3;
            float v23 = __shfl_xor(u23, 1);
            float B = ((lane & 1) ? b3 : b2) + v23;
            float uu = (lane & 2) ? A : B;
            float vv = __shfl_xor(uu, 2);
            float S = ((lane & 2) ? B : A) + vv;     // lane 4g+r holds r-comp sum over group g (16 cols)
            const int row = w * 16 + t;
            part[row][((lane >> 2) + row) & 15][lane & 3] = S;
        }
        __syncthreads();
        if (threadIdx.x < 64) {
            const int row = threadIdx.x;
            float4 acc; acc.x = 0.f; acc.y = 0.f; acc.z = 0.f; acc.w = 0.f;
            #pragma unroll
            for (int k = 0; k < 16; ++k) {
                const float4 p = *(const float4*)&part[row][(k + row) & 15][0];
                acc.x += p.x; acc.y += p.y; acc.z += p.z; acc.w += p.w;
            }
            const int i = i00 + row;
            atomicAdd(&bwd[i * 4 + 0], acc.x);
            atomicAdd(&bwd[i * 4 + 1], acc.y);
            atomicAdd(&bwd[i * 4 + 2], acc.z);
            atomicAdd(&bwd[i * 4 + 3], acc.w);
        }
        __syncthreads();
    }
    // fwd combine: one atomic set per column
    #pragma unroll
    for (int a = 0; a < 4; a++)
        #pragma unroll
        for (int r = 0; r < 4; r++)
            fl[w][lane * 4 + a][r] = fa[a][r];
    __syncthreads();
    const int col = threadIdx.x;
    const float4 s0 = *(const float4*)&fl[0][col][0];
    const float4 s1 = *(const float4*)&fl[1][col][0];
    const float4 s2 = *(const float4*)&fl[2][col][0];
    const float4 s3 = *(const float4*)&fl[3][col][0];
    atomicAdd(&fwd[(blockIdx.x * 256 + col) * 4 + 0], s0.x + s1.x + s2.x + s3.x);
    atomicAdd(&fwd[(blockIdx.x * 256 + col) * 4 + 1], s0.y + s1.y + s2.y + s3.y);
    atomicAdd(&fwd[(blockIdx.x * 256 + col) * 4 + 2], s0.z + s1.z + s2.z + s3.z);
    atomicAdd(&fwd[(blockIdx.x * 256 + col) * 4 + 3], s0.w + s1.w + s2.w + s3.w);
}

// ---- combine into new read weightings ----
__global__ void k_final(const float* __restrict__ fwd, const float* __restrict__ bwd,
                        const float* __restrict__ rc, const float* __restrict__ modes,
                        float* __restrict__ out) {
    int idx = blockIdx.x * 256 + threadIdx.x;   // < 32768
    int r = idx & 3;
    float m0 = modes[r * 3], m1 = modes[r * 3 + 1], m2 = modes[r * 3 + 2];
    out[idx] = bwd[idx] * m0 + rc[idx] * m1 + fwd[idx] * m2;
}

extern "C" void kernel_launch(void* const* d_in, const int* in_sizes, int n_in,
                              void* d_out, int out_size, void* d_ws, size_t ws_size,
                              hipStream_t stream) {
    const float* mem   = (const float*)d_in[0];
    const float* u     = (const float*)d_in[1];
    const float* prec  = (const float*)d_in[2];
    const float* link  = (const float*)d_in[3];
    const float* rw    = (const float*)d_in[4];
    const float* rk    = (const float*)d_in[5];
    const float* rstr  = (const float*)d_in[6];
    const float* wk    = (const float*)d_in[7];
    const float* wstr  = (const float*)d_in[8];
    const float* er    = (const float*)d_in[9];
    const float* wv    = (const float*)d_in[10];
    const float* fg    = (const float*)d_in[11];
    const float* ag    = (const float*)d_in[12];
    const float* wg    = (const float*)d_in[13];
    const float* modes = (const float*)d_in[14];
    float* out = (float*)d_out;
    float* ws  = (float*)d_ws;
    float* nlr = out + O_NL;   // big scratch inside the not-yet-written new_link region

    (void)hipMemsetAsync(ws + S_SCAL, 0, 32 * sizeof(float), stream);

    k_rowstats<<<256, 256, 0, stream>>>(mem, rw, wk, fg, wstr,
                                        nlr + P_RVP, ws + S_LOGITS, ws + S_RET, ws + S_SCAL);
    k_apart<<<512, 256, 0, stream>>>(u, nlr + P_APART, nlr + P_CPART, ws + S_FWD);
    k_grank<<<32, 256, 0, stream>>>(u, nlr + P_APART, nlr + P_CPART, nlr + P_RVP,
                                    ws + S_G, (int*)(ws + S_RANK), ws + S_SCAL, out + O_RV);
    k_scatter<<<32, 256, 0, stream>>>(ws + S_G, (const int*)(ws + S_RANK), ws + S_ALLOC);
    k_rownew<<<512, 256, 0, stream>>>(mem, ws + S_LOGITS, ws + S_ALLOC, u, ws + S_RET,
                                      prec, er, wv, rk, rstr, ag, wg, ws + S_SCAL,
                                      ws + S_WW, out + O_NM, out + O_NU, out + O_NP, ws + S_RC);
    dim3 lg(32, 32);
    k_link<<<lg, 256, 0, stream>>>(link, ws + S_WW, prec, rw, out + O_NL, ws + S_FWD, ws + S_BWD);
    k_final<<<128, 256, 0, stream>>>(ws + S_FWD, ws + S_BWD, ws + S_RC, modes, out + O_NR);
}